// Round 1
// baseline (241.091 us; speedup 1.0000x reference)
//
#include <hip/hip_runtime.h>
#include <stdint.h>
#include <stddef.h>

#define NN 8192
#define DD 256
#define HH 128

typedef short bf16x8 __attribute__((ext_vector_type(8)));
typedef float f32x4  __attribute__((ext_vector_type(4)));
typedef int   i32x4  __attribute__((ext_vector_type(4)));

// f32 -> bf16 round-to-nearest-even (bit recipe, matches HW RNE for finite vals)
static __device__ __forceinline__ short f2bf(float x){
  unsigned u = __float_as_uint(x);
  u = (u + 0x7FFFu + ((u >> 16) & 1u)) >> 16;
  return (short)(unsigned short)u;
}

static __device__ __forceinline__ bf16x8 cvt8(const float* p){ // 8 f32 -> 8 bf16
  f32x4 a = *(const f32x4*)p;
  f32x4 b = *(const f32x4*)(p + 4);
  bf16x8 o;
  o[0]=f2bf(a[0]); o[1]=f2bf(a[1]); o[2]=f2bf(a[2]); o[3]=f2bf(a[3]);
  o[4]=f2bf(b[0]); o[5]=f2bf(b[1]); o[6]=f2bf(b[2]); o[7]=f2bf(b[3]);
  return o;
}

static __device__ __forceinline__ bf16x8 ld16(const void* p){ // 16B load as bf16x8
  i32x4 v = *(const i32x4*)p;
  return __builtin_bit_cast(bf16x8, v);
}

// ---------------- features [N][D] f32 -> featT [D][N] bf16 ----------------
__global__ __launch_bounds__(256) void k_transpose(const float* __restrict__ f,
                                                   unsigned short* __restrict__ ft){
  __shared__ unsigned short tile[64][65];  // +1 pad breaks bank alias
  int t  = threadIdx.x;
  int i0 = blockIdx.x * 64, d0 = blockIdx.y * 64;
  int r0 = t >> 6, c = t & 63;
  for (int it = 0; it < 16; ++it){
    int r = r0 + it * 4;
    tile[c][r] = (unsigned short)f2bf(f[(size_t)(i0 + r) * DD + d0 + c]);
  }
  __syncthreads();
  for (int it = 0; it < 16; ++it){
    int rr = r0 + it * 4;
    ft[(size_t)(d0 + rr) * NN + i0 + c] = tile[rr][c];
  }
}

// ---------------- projections: Qn/Kn = cos-normalized (features @ W^T), bf16 ----------------
// MFMA GEMM: A = features rows (A-frag: row=l&15, k=8*(l>>4)+t contiguous),
// B[k=d][col=h] = W[h][d] -> contiguous along d. C/D: col=lane&15, row=(lane>>4)*4+reg.
__global__ __launch_bounds__(256) void k_proj(const float* __restrict__ f,
                                              const float* __restrict__ Wq,
                                              const float* __restrict__ Wk,
                                              unsigned short* __restrict__ Qn,
                                              unsigned short* __restrict__ Kn){
  int t = threadIdx.x, wave = t >> 6, l = t & 63;
  int i0 = blockIdx.x * 64 + wave * 16;
  int lr = l & 15, lk = l >> 4;
  bf16x8 ka[8];
  for (int ks = 0; ks < 8; ++ks)
    ka[ks] = cvt8(f + (size_t)(i0 + lr) * DD + ks * 32 + lk * 8);
  for (int pj = 0; pj < 2; ++pj){
    const float* W = pj ? Wk : Wq;
    unsigned short* out = pj ? Kn : Qn;
    f32x4 acc[8];
    for (int n = 0; n < 8; ++n) acc[n] = (f32x4){0.f,0.f,0.f,0.f};
    for (int ks = 0; ks < 8; ++ks)
      for (int n = 0; n < 8; ++n){
        bf16x8 bb = cvt8(W + (size_t)(n * 16 + lr) * DD + ks * 32 + lk * 8);
        acc[n] = __builtin_amdgcn_mfma_f32_16x16x32_bf16(ka[ks], bb, acc[n], 0, 0, 0);
      }
    for (int r = 0; r < 4; ++r){
      float n2 = 0.f;
      for (int n = 0; n < 8; ++n){ float v = acc[n][r]; n2 += v * v; }
      n2 += __shfl_xor(n2, 1); n2 += __shfl_xor(n2, 2);
      n2 += __shfl_xor(n2, 4); n2 += __shfl_xor(n2, 8);
      float s = 1.f / fmaxf(sqrtf(n2), 1e-4f);   // torch cosine eps
      int row = i0 + lk * 4 + r;
      for (int n = 0; n < 8; ++n)
        out[(size_t)row * HH + n * 16 + lr] = (unsigned short)f2bf(acc[n][r] * s);
    }
  }
}

// ---------------- fused masked-softmax attention ----------------
// Block: 64 i-rows x (1/4 of j), 4 waves. Per 64-wide j-step:
//  stage Qn[64][128] + featT[256][64] into XOR-swizzled LDS, nt-load adj,
//  QK^T MFMA -> w = adj ? exp(s) : 0 -> W tile via swizzled LDS -> PV MFMA.
// Partial num/den accumulated, atomically added at the end (4 j-splits).
__global__ __launch_bounds__(256, 2) void k_attn(const int* __restrict__ adj,
      const unsigned short* __restrict__ Qn, const unsigned short* __restrict__ Kn,
      const unsigned short* __restrict__ ft,
      float* __restrict__ num, float* __restrict__ den){
  __shared__ __align__(16) char smem[57344];
  char* qn_s = smem;           // [64 j][256B] swizzled
  char* ft_s = smem + 16384;   // [256 d][128B] swizzled
  char* w_s  = smem + 49152;   // [64 i][128B] swizzled
  int t = threadIdx.x, wave = t >> 6, l = t & 63;
  int ib = blockIdx.x >> 2, js = blockIdx.x & 3;
  int i0 = ib * 64;
  int jbase = js * 2048;
  int lr = l & 15, lk = l >> 4;
  int swz = (l & 7) << 4;      // read-side swizzle (row&7 == l&7 on all frag reads)
  bf16x8 ka[4];
  {
    const unsigned short* kp = Kn + (size_t)(i0 + wave * 16 + lr) * HH;
    for (int ks = 0; ks < 4; ++ks) ka[ks] = ld16(kp + ks * 32 + lk * 8);
  }
  f32x4 pv[2][8];
  for (int a = 0; a < 2; ++a) for (int b = 0; b < 8; ++b) pv[a][b] = (f32x4){0.f,0.f,0.f,0.f};
  float dacc[4] = {0.f, 0.f, 0.f, 0.f};
  int rgp = wave & 1, dh = wave >> 1;
  int qrow = t >> 4, qc = t & 15;
  int frow = t >> 3, fc = t & 7;

  for (int step = 0; step < 32; ++step){
    int j0 = jbase + step * 64;
    __syncthreads();                       // prev PV readers done
    for (int it = 0; it < 4; ++it){        // stage Qn slab (16KB)
      int r = qrow + it * 16;
      i32x4 v = *(const i32x4*)(Qn + (size_t)(j0 + r) * HH + qc * 8);
      *(i32x4*)(qn_s + r * 256 + ((qc * 16) ^ ((r & 7) << 4))) = v;
    }
    for (int it = 0; it < 8; ++it){        // stage featT slab (32KB)
      int d2 = frow + it * 32;
      i32x4 v = *(const i32x4*)(ft + (size_t)d2 * NN + j0 + fc * 8);
      *(i32x4*)(ft_s + d2 * 128 + ((fc * 16) ^ ((d2 & 7) << 4))) = v;
    }
    int adjv[4][4];                        // adj tile, nontemporal (streamed once)
    for (int r = 0; r < 4; ++r){
      const int* ap = adj + (size_t)(i0 + wave * 16 + lk * 4 + r) * NN + j0 + lr;
      for (int cg = 0; cg < 4; ++cg)
        adjv[cg][r] = __builtin_nontemporal_load(ap + cg * 16);
    }
    __syncthreads();                       // staging visible
    f32x4 sa[4];
    for (int cg = 0; cg < 4; ++cg) sa[cg] = (f32x4){0.f,0.f,0.f,0.f};
    for (int ks = 0; ks < 4; ++ks){
      int kb = (ks * 64 + lk * 16) ^ swz;
      for (int cg = 0; cg < 4; ++cg){
        bf16x8 bq = ld16(qn_s + (cg * 16 + lr) * 256 + kb);
        sa[cg] = __builtin_amdgcn_mfma_f32_16x16x32_bf16(ka[ks], bq, sa[cg], 0, 0, 0);
      }
    }
    for (int cg = 0; cg < 4; ++cg)
      for (int r = 0; r < 4; ++r){
        float w = adjv[cg][r] > 0 ? __expf(sa[cg][r]) : 0.f;  // scores in [-1,1]: no max needed
        dacc[r] += w;
        int row = wave * 16 + lk * 4 + r;
        *(unsigned short*)(w_s + row * 128 + ((cg * 32 + lr * 2) ^ ((row & 7) << 4)))
            = (unsigned short)f2bf(w);
      }
    __syncthreads();                       // W visible
    for (int ks = 0; ks < 2; ++ks){
      int kb = (ks * 64 + lk * 16) ^ swz;
      bf16x8 a0 = ld16(w_s + (rgp * 32 + lr) * 128 + kb);
      bf16x8 a1 = ld16(w_s + (rgp * 32 + 16 + lr) * 128 + kb);
      for (int dn = 0; dn < 8; ++dn){
        int dl = dh * 128 + dn * 16 + lr;
        bf16x8 bv = ld16(ft_s + dl * 128 + kb);
        pv[0][dn] = __builtin_amdgcn_mfma_f32_16x16x32_bf16(a0, bv, pv[0][dn], 0, 0, 0);
        pv[1][dn] = __builtin_amdgcn_mfma_f32_16x16x32_bf16(a1, bv, pv[1][dn], 0, 0, 0);
      }
    }
  }
  for (int r = 0; r < 4; ++r){
    float v = dacc[r];
    v += __shfl_xor(v, 1); v += __shfl_xor(v, 2);
    v += __shfl_xor(v, 4); v += __shfl_xor(v, 8);
    if (lr == 0) atomicAdd(&den[i0 + wave * 16 + lk * 4 + r], v);
  }
  for (int rgi = 0; rgi < 2; ++rgi)
    for (int dn = 0; dn < 8; ++dn)
      for (int r = 0; r < 4; ++r){
        int row = i0 + rgp * 32 + rgi * 16 + lk * 4 + r;
        int col = dh * 128 + dn * 16 + lr;
        atomicAdd(&num[(size_t)row * DD + col], pv[rgi][dn][r]);
      }
}

// ---------------- finalize: out = den>0 ? 0.5*num/den + 0.5*f : f ----------------
__global__ __launch_bounds__(256) void k_final(const float* __restrict__ num,
                                               const float* __restrict__ den,
                                               const float* __restrict__ f,
                                               float* __restrict__ out){
  int gid = blockIdx.x * 256 + threadIdx.x;   // one float4 per thread, exact grid
  int i = gid >> 6;                            // 64 float4 per row (D=256)
  f32x4 nv = *(const f32x4*)(num + (size_t)gid * 4);
  f32x4 fv = *(const f32x4*)(f   + (size_t)gid * 4);
  float dv = den[i];
  f32x4 o;
  if (dv > 0.f){
    float inv = 0.5f / dv;
    o = nv * inv + fv * 0.5f;
  } else {
    o = fv;                                    // no-neighbor row keeps features
  }
  *(f32x4*)(out + (size_t)gid * 4) = o;
}

extern "C" void kernel_launch(void* const* d_in, const int* in_sizes, int n_in,
                              void* d_out, int out_size, void* d_ws, size_t ws_size,
                              hipStream_t stream){
  (void)in_sizes; (void)n_in; (void)out_size;
  const float* feat = (const float*)d_in[0];
  const int*   adj  = (const int*)d_in[1];
  const float* Wq   = (const float*)d_in[2];
  const float* Wk   = (const float*)d_in[3];
  float* out = (float*)d_out;
  char* ws = (char*)d_ws;
  unsigned short* Qn = (unsigned short*)(ws);                     // 2MB
  unsigned short* Kn = (unsigned short*)(ws + (2u << 20));        // 2MB
  unsigned short* ft = (unsigned short*)(ws + (4u << 20));        // 4MB
  float* num = (float*)(ws + (8u << 20));                         // 8MB
  float* den = (float*)(ws + (16u << 20));                        // 32KB
  if (ws_size < (16u << 20) + 32768u) return;                     // need ~16.03MB scratch

  hipMemsetAsync(num, 0, (8u << 20) + 32768u, stream);            // zero num+den
  k_transpose<<<dim3(128, 4), 256, 0, stream>>>(feat, ft);
  k_proj<<<128, 256, 0, stream>>>(feat, Wq, Wk, Qn, Kn);
  k_attn<<<512, 256, 0, stream>>>(adj, Qn, Kn, ft, num, den);
  k_final<<<2048, 256, 0, stream>>>(num, den, feat, out);
}

// Round 2
// 233.034 us; speedup vs baseline: 1.0346x; 1.0346x over previous
//
#include <hip/hip_runtime.h>
#include <stdint.h>
#include <stddef.h>

#define NN 8192
#define DD 256
#define HH 128

typedef short bf16x8 __attribute__((ext_vector_type(8)));
typedef float f32x4  __attribute__((ext_vector_type(4)));
typedef int   i32x4  __attribute__((ext_vector_type(4)));

// f32 -> bf16 round-to-nearest-even (bit recipe, matches HW RNE for finite vals)
static __device__ __forceinline__ short f2bf(float x){
  unsigned u = __float_as_uint(x);
  u = (u + 0x7FFFu + ((u >> 16) & 1u)) >> 16;
  return (short)(unsigned short)u;
}

static __device__ __forceinline__ bf16x8 cvt8(const float* p){ // 8 f32 -> 8 bf16
  f32x4 a = *(const f32x4*)p;
  f32x4 b = *(const f32x4*)(p + 4);
  bf16x8 o;
  o[0]=f2bf(a[0]); o[1]=f2bf(a[1]); o[2]=f2bf(a[2]); o[3]=f2bf(a[3]);
  o[4]=f2bf(b[0]); o[5]=f2bf(b[1]); o[6]=f2bf(b[2]); o[7]=f2bf(b[3]);
  return o;
}

static __device__ __forceinline__ bf16x8 ld16(const void* p){ // 16B load as bf16x8
  i32x4 v = *(const i32x4*)p;
  return __builtin_bit_cast(bf16x8, v);
}

// ---------------- features [N][D] f32 -> featT [D][N] bf16 ----------------
__global__ __launch_bounds__(256) void k_transpose(const float* __restrict__ f,
                                                   unsigned short* __restrict__ ft){
  __shared__ unsigned short tile[64][65];  // +1 pad breaks bank alias
  int t  = threadIdx.x;
  int i0 = blockIdx.x * 64, d0 = blockIdx.y * 64;
  int r0 = t >> 6, c = t & 63;
  for (int it = 0; it < 16; ++it){
    int r = r0 + it * 4;
    tile[c][r] = (unsigned short)f2bf(f[(size_t)(i0 + r) * DD + d0 + c]);
  }
  __syncthreads();
  for (int it = 0; it < 16; ++it){
    int rr = r0 + it * 4;
    ft[(size_t)(d0 + rr) * NN + i0 + c] = tile[rr][c];
  }
}

// ---------------- projections: Qn/Kn = cos-normalized (features @ W^T), bf16 ----------------
__global__ __launch_bounds__(256) void k_proj(const float* __restrict__ f,
                                              const float* __restrict__ Wq,
                                              const float* __restrict__ Wk,
                                              unsigned short* __restrict__ Qn,
                                              unsigned short* __restrict__ Kn){
  int t = threadIdx.x, wave = t >> 6, l = t & 63;
  int i0 = blockIdx.x * 64 + wave * 16;
  int lr = l & 15, lk = l >> 4;
  bf16x8 ka[8];
  for (int ks = 0; ks < 8; ++ks)
    ka[ks] = cvt8(f + (size_t)(i0 + lr) * DD + ks * 32 + lk * 8);
  for (int pj = 0; pj < 2; ++pj){
    const float* W = pj ? Wk : Wq;
    unsigned short* out = pj ? Kn : Qn;
    f32x4 acc[8];
    for (int n = 0; n < 8; ++n) acc[n] = (f32x4){0.f,0.f,0.f,0.f};
    for (int ks = 0; ks < 8; ++ks)
      for (int n = 0; n < 8; ++n){
        bf16x8 bb = cvt8(W + (size_t)(n * 16 + lr) * DD + ks * 32 + lk * 8);
        acc[n] = __builtin_amdgcn_mfma_f32_16x16x32_bf16(ka[ks], bb, acc[n], 0, 0, 0);
      }
    for (int r = 0; r < 4; ++r){
      float n2 = 0.f;
      for (int n = 0; n < 8; ++n){ float v = acc[n][r]; n2 += v * v; }
      n2 += __shfl_xor(n2, 1); n2 += __shfl_xor(n2, 2);
      n2 += __shfl_xor(n2, 4); n2 += __shfl_xor(n2, 8);
      float s = 1.f / fmaxf(sqrtf(n2), 1e-4f);   // torch cosine eps
      int row = i0 + lk * 4 + r;
      for (int n = 0; n < 8; ++n)
        out[(size_t)row * HH + n * 16 + lr] = (unsigned short)f2bf(acc[n][r] * s);
    }
  }
}

// ---------------- fused masked-softmax attention ----------------
// Block: 64 i-rows x (1/4 of j), 4 waves. Per 64-wide j-step:
//  stage Qn[64][128] + featT[256][64] into XOR-swizzled LDS, nt-load adj,
//  QK^T MFMA -> w = adj ? exp(s) : 0 -> W tile via swizzled LDS -> PV MFMA.
// Partials written with PLAIN STORES to per-split regions (no memset, no atomics).
__global__ __launch_bounds__(256, 2) void k_attn(const int* __restrict__ adj,
      const unsigned short* __restrict__ Qn, const unsigned short* __restrict__ Kn,
      const unsigned short* __restrict__ ft,
      float* __restrict__ num_p, float* __restrict__ den_p){
  __shared__ __align__(16) char smem[57344];
  char* qn_s = smem;           // [64 j][256B] swizzled
  char* ft_s = smem + 16384;   // [256 d][128B] swizzled
  char* w_s  = smem + 49152;   // [64 i][128B] swizzled
  int t = threadIdx.x, wave = t >> 6, l = t & 63;
  int ib = blockIdx.x >> 2, js = blockIdx.x & 3;
  int i0 = ib * 64;
  int jbase = js * 2048;
  int lr = l & 15, lk = l >> 4;
  int swz = (l & 7) << 4;      // read-side swizzle (row&7 == l&7 on all frag reads)
  bf16x8 ka[4];
  {
    const unsigned short* kp = Kn + (size_t)(i0 + wave * 16 + lr) * HH;
    for (int ks = 0; ks < 4; ++ks) ka[ks] = ld16(kp + ks * 32 + lk * 8);
  }
  f32x4 pv[2][8];
  for (int a = 0; a < 2; ++a) for (int b = 0; b < 8; ++b) pv[a][b] = (f32x4){0.f,0.f,0.f,0.f};
  float dacc[4] = {0.f, 0.f, 0.f, 0.f};
  int rgp = wave & 1, dh = wave >> 1;
  int qrow = t >> 4, qc = t & 15;
  int frow = t >> 3, fc = t & 7;

  for (int step = 0; step < 32; ++step){
    int j0 = jbase + step * 64;
    __syncthreads();                       // prev PV readers done
    for (int it = 0; it < 4; ++it){        // stage Qn slab (16KB)
      int r = qrow + it * 16;
      i32x4 v = *(const i32x4*)(Qn + (size_t)(j0 + r) * HH + qc * 8);
      *(i32x4*)(qn_s + r * 256 + ((qc * 16) ^ ((r & 7) << 4))) = v;
    }
    for (int it = 0; it < 8; ++it){        // stage featT slab (32KB)
      int d2 = frow + it * 32;
      i32x4 v = *(const i32x4*)(ft + (size_t)d2 * NN + j0 + fc * 8);
      *(i32x4*)(ft_s + d2 * 128 + ((fc * 16) ^ ((d2 & 7) << 4))) = v;
    }
    int adjv[4][4];                        // adj tile, nontemporal (streamed once)
    for (int r = 0; r < 4; ++r){
      const int* ap = adj + (size_t)(i0 + wave * 16 + lk * 4 + r) * NN + j0 + lr;
      for (int cg = 0; cg < 4; ++cg)
        adjv[cg][r] = __builtin_nontemporal_load(ap + cg * 16);
    }
    __syncthreads();                       // staging visible
    f32x4 sa[4];
    for (int cg = 0; cg < 4; ++cg) sa[cg] = (f32x4){0.f,0.f,0.f,0.f};
    for (int ks = 0; ks < 4; ++ks){
      int kb = (ks * 64 + lk * 16) ^ swz;
      for (int cg = 0; cg < 4; ++cg){
        bf16x8 bq = ld16(qn_s + (cg * 16 + lr) * 256 + kb);
        sa[cg] = __builtin_amdgcn_mfma_f32_16x16x32_bf16(ka[ks], bq, sa[cg], 0, 0, 0);
      }
    }
    for (int cg = 0; cg < 4; ++cg)
      for (int r = 0; r < 4; ++r){
        float w = adjv[cg][r] > 0 ? __expf(sa[cg][r]) : 0.f;  // scores in [-1,1]: no max needed
        dacc[r] += w;
        int row = wave * 16 + lk * 4 + r;
        *(unsigned short*)(w_s + row * 128 + ((cg * 32 + lr * 2) ^ ((row & 7) << 4)))
            = (unsigned short)f2bf(w);
      }
    __syncthreads();                       // W visible
    for (int ks = 0; ks < 2; ++ks){
      int kb = (ks * 64 + lk * 16) ^ swz;
      bf16x8 a0 = ld16(w_s + (rgp * 32 + lr) * 128 + kb);
      bf16x8 a1 = ld16(w_s + (rgp * 32 + 16 + lr) * 128 + kb);
      for (int dn = 0; dn < 8; ++dn){
        int dl = dh * 128 + dn * 16 + lr;
        bf16x8 bv = ld16(ft_s + dl * 128 + kb);
        pv[0][dn] = __builtin_amdgcn_mfma_f32_16x16x32_bf16(a0, bv, pv[0][dn], 0, 0, 0);
        pv[1][dn] = __builtin_amdgcn_mfma_f32_16x16x32_bf16(a1, bv, pv[1][dn], 0, 0, 0);
      }
    }
  }
  // den partial: wave-group reduce then plain store (one row per (lk,r) at lr==0)
  for (int r = 0; r < 4; ++r){
    float v = dacc[r];
    v += __shfl_xor(v, 1); v += __shfl_xor(v, 2);
    v += __shfl_xor(v, 4); v += __shfl_xor(v, 8);
    if (lr == 0) den_p[(size_t)js * NN + i0 + wave * 16 + lk * 4 + r] = v;
  }
  // num partial: plain stores into this split's region (no atomics)
  float* np = num_p + (size_t)js * NN * DD;
  for (int rgi = 0; rgi < 2; ++rgi)
    for (int dn = 0; dn < 8; ++dn)
      for (int r = 0; r < 4; ++r){
        int row = i0 + rgp * 32 + rgi * 16 + lk * 4 + r;
        int col = dh * 128 + dn * 16 + lr;
        np[(size_t)row * DD + col] = pv[rgi][dn][r];
      }
}

// ---------------- finalize: sum 4 partials; out = den>0 ? 0.5*num/den + 0.5*f : f ----------------
__global__ __launch_bounds__(256) void k_final(const float* __restrict__ num_p,
                                               const float* __restrict__ den_p,
                                               const float* __restrict__ f,
                                               float* __restrict__ out){
  int gid = blockIdx.x * 256 + threadIdx.x;   // one float4 per thread, exact grid
  int i = gid >> 6;                            // 64 float4 per row (D=256)
  f32x4 nv = (f32x4){0.f,0.f,0.f,0.f};
  float dv = 0.f;
  for (int s = 0; s < 4; ++s){
    nv += *(const f32x4*)(num_p + (size_t)s * NN * DD + (size_t)gid * 4);
    dv += den_p[(size_t)s * NN + i];
  }
  f32x4 fv = *(const f32x4*)(f + (size_t)gid * 4);
  f32x4 o;
  if (dv > 0.f){
    float inv = 0.5f / dv;
    o = nv * inv + fv * 0.5f;
  } else {
    o = fv;                                    // no-neighbor row keeps features
  }
  *(f32x4*)(out + (size_t)gid * 4) = o;
}

extern "C" void kernel_launch(void* const* d_in, const int* in_sizes, int n_in,
                              void* d_out, int out_size, void* d_ws, size_t ws_size,
                              hipStream_t stream){
  (void)in_sizes; (void)n_in; (void)out_size;
  const float* feat = (const float*)d_in[0];
  const int*   adj  = (const int*)d_in[1];
  const float* Wq   = (const float*)d_in[2];
  const float* Wk   = (const float*)d_in[3];
  float* out = (float*)d_out;
  char* ws = (char*)d_ws;
  unsigned short* Qn = (unsigned short*)(ws);                     // 2MB
  unsigned short* Kn = (unsigned short*)(ws + (2u << 20));        // 2MB
  unsigned short* ft = (unsigned short*)(ws + (4u << 20));        // 4MB
  float* num_p = (float*)(ws + (8u << 20));                       // 4 x 8MB partials
  float* den_p = (float*)(ws + (40u << 20));                      // 4 x 32KB partials
  if (ws_size < (40u << 20) + (4u * NN * 4u)) return;             // need ~40.13MB scratch

  // no memset, no atomics: every ws byte consumed below is written first
  k_transpose<<<dim3(128, 4), 256, 0, stream>>>(feat, ft);
  k_proj<<<128, 256, 0, stream>>>(feat, Wq, Wk, Qn, Kn);
  k_attn<<<512, 256, 0, stream>>>(adj, Qn, Kn, ft, num_p, den_p);
  k_final<<<2048, 256, 0, stream>>>(num_p, den_p, feat, out);
}